// Round 2
// baseline (2428.144 us; speedup 1.0000x reference)
//
#include <hip/hip_runtime.h>
#include <hip/hip_bf16.h>
#include <cstddef>

// ---------------------------------------------------------------------------
// VSSM (VMamba SS2D) forward. B=8, H=W=64, L=4096, D=384, Din=768, N=16,
// R=24, K=4 directions.
// Pipeline (per batch-chunk of BCH images, BCH picked from ws_size):
//   K1  gemm: xz = x @ W_in (M x 384 x 1536), epilogue splits xm / silu(z)
//   K2  depthwise 3x3 conv + silu -> xc
//   K3  gemm: proj = xc @ x_proj_weight^T stacked (M x 768 x 224), position-space
//   scan: chunked (16 chunks of 256 steps), 3 phases; delta recomputed
//         in-scan; y contributions atomicAdd'ed into y_comb (+ D*u term)
//   K4  layernorm(y) * silu(z)
//   K5  gemm: out = y_norm @ W_out (M x 768 x 384)
// Workspace aliases: y_comb <- xm region, y_norm <- xc region, Hin <- Pbuf.
// ---------------------------------------------------------------------------

#define LL 4096
#define DIN 768
#define NSTATE 16
#define RRANK 24
#define NCHUNK 16
#define CHLEN 256   // LL / NCHUNK

__device__ __forceinline__ float silu_f(float x) {
    return x / (1.f + __expf(-x));
}
__device__ __forceinline__ float softplus_f(float x) {
    return (x > 15.f) ? x : __logf(1.f + __expf(x));
}
// spatial position read/written by direction k at scan step t
__device__ __forceinline__ int pos_of(int k, int t) {
    int tt = (k >= 2) ? (LL - 1 - t) : t;
    if (k & 1) return (tt & 63) * 64 + (tt >> 6);  // transpose WH <-> HW
    return tt;
}

// ---------------------------------------------------------------------------
// fp32 tiled GEMM: C[M,Nf] = A[M,Kd] @ B[Kd,Nf]. TM=128, KT=16.
// EPI==0: plain store to out0 (stride Nf)
// EPI==1: split: col<768 -> out0 (xm), col>=768 -> out1 = silu (z-gate)
// ---------------------------------------------------------------------------
template<int TN, int EPI>
__global__ __launch_bounds__(256) void gemm_f32(
    const float* __restrict__ A, const float* __restrict__ Bm,
    float* __restrict__ out0, float* __restrict__ out1,
    int M, int Kd, int Nf)
{
    constexpr int CW = TN / 8;
    __shared__ float As[16][132];   // transposed A tile (132*4B keeps 16B align)
    __shared__ float Bs[16][TN];
    const int tid = threadIdx.x;
    const int bx = blockIdx.x, by = blockIdx.y;
    const int tr = tid & 31, tc = tid >> 5;        // 32 x 8 thread grid
    const int r0 = tr * 4, c0 = tc * CW;           // micro-tile 4 x CW

    float acc[4][CW];
#pragma unroll
    for (int i = 0; i < 4; ++i)
#pragma unroll
        for (int j = 0; j < CW; ++j) acc[i][j] = 0.f;

    for (int kt = 0; kt < Kd; kt += 16) {
        __syncthreads();
#pragma unroll
        for (int j = 0; j < 2; ++j) {
            int idx = tid + j * 256;               // 512 float4 units
            int r = idx >> 2, c4 = (idx & 3) * 4;
            const float4 va = *(const float4*)(A + (size_t)(by * 128 + r) * Kd + kt + c4);
            As[c4 + 0][r] = va.x; As[c4 + 1][r] = va.y;
            As[c4 + 2][r] = va.z; As[c4 + 3][r] = va.w;
        }
        for (int i = tid; i < 16 * TN / 4; i += 256) {
            int r = i / (TN / 4), c4 = (i % (TN / 4)) * 4;
            *(float4*)(&Bs[r][c4]) =
                *(const float4*)(Bm + (size_t)(kt + r) * Nf + bx * TN + c4);
        }
        __syncthreads();
#pragma unroll
        for (int kk = 0; kk < 16; ++kk) {
            float4 a4 = *(const float4*)(&As[kk][r0]);
            float av[4] = {a4.x, a4.y, a4.z, a4.w};
            float bv[CW];
#pragma unroll
            for (int j = 0; j < CW; ++j) bv[j] = Bs[kk][c0 + j];
#pragma unroll
            for (int i = 0; i < 4; ++i)
#pragma unroll
                for (int j = 0; j < CW; ++j)
                    acc[i][j] = fmaf(av[i], bv[j], acc[i][j]);
        }
    }
#pragma unroll
    for (int i = 0; i < 4; ++i) {
        int row = by * 128 + r0 + i;
#pragma unroll
        for (int j = 0; j < CW; ++j) {
            int col = bx * TN + c0 + j;
            float v = acc[i][j];
            if (EPI == 0) {
                out0[(size_t)row * Nf + col] = v;
            } else {
                if (col < DIN) out0[(size_t)row * DIN + col] = v;
                else           out1[(size_t)row * DIN + (col - DIN)] = silu_f(v);
            }
        }
    }
}

// depthwise 3x3 conv (pad 1) + silu.  xm,(NB,L,Din) -> xc,(NB,L,Din)
__global__ __launch_bounds__(256) void dwconv_silu(
    const float* __restrict__ xm, const float* __restrict__ cw,
    const float* __restrict__ cb, float* __restrict__ xc)
{
    const int bl = blockIdx.x;
    const int d = blockIdx.y * 256 + threadIdx.x;
    const int b = bl >> 12, l = bl & 4095;
    const int h = l >> 6, w = l & 63;
    float acc = cb[d];
#pragma unroll
    for (int i = 0; i < 3; ++i) {
        int hh = h + i - 1;
        if (hh < 0 || hh > 63) continue;
#pragma unroll
        for (int j = 0; j < 3; ++j) {
            int ww = w + j - 1;
            if (ww < 0 || ww > 63) continue;
            acc = fmaf(xm[((size_t)(b << 12) + (hh << 6) + ww) * DIN + d],
                       cw[d * 9 + i * 3 + j], acc);
        }
    }
    xc[(size_t)bl * DIN + d] = silu_f(acc);
}

// x_proj_weight (K,56,Din) -> (Din, 224) row-major for the GEMM
__global__ void transpose_xpw(const float* __restrict__ xpw, float* __restrict__ out) {
    int idx = blockIdx.x * 256 + threadIdx.x;
    if (idx >= DIN * 224) return;
    int d = idx / 224, j = idx % 224;
    out[idx] = xpw[(size_t)j * DIN + d];
}

__global__ void zero_fill(float4* __restrict__ p, int n4) {
    int i = blockIdx.x * 256 + threadIdx.x;
    if (i < n4) p[i] = make_float4(0.f, 0.f, 0.f, 0.f);
}

// ---------------------------------------------------------------------------
// Chunked selective scan.
// Phase 1: per (b,k,chunk,d): local scan with h_in=0; emit per-state
//          a-product P[16] and local final state Hloc[16].
// Phase 2: sequential combine over chunks -> Hin per chunk (Hin may alias P).
// Phase 3: replay with correct Hin, produce y = sum_n h*C + D*u,
//          atomicAdd into y_comb at the source position.
// Summary layout: [(b*4+k)*16 + s][d*16 + n]  (stride 12288)
// ---------------------------------------------------------------------------
__global__ __launch_bounds__(768) void scan_phase1(
    const float* __restrict__ xc, const float* __restrict__ proj,
    const float* __restrict__ dtw_all, const float* __restrict__ dtb_all,
    const float* __restrict__ A_logs,
    float* __restrict__ Pout, float* __restrict__ Hloc)
{
    const int s = blockIdx.x, k = blockIdx.y, b = blockIdx.z;
    const int d = threadIdx.x;
    __shared__ float lds[8][56];

    float dtw[RRANK];
    const float* wp = dtw_all + ((size_t)(k * DIN + d)) * RRANK;
#pragma unroll
    for (int r = 0; r < RRANK; ++r) dtw[r] = wp[r];
    const float bias = dtb_all[k * DIN + d];
    float Arow[NSTATE];
    const float* ap = A_logs + ((size_t)(k * DIN + d)) * NSTATE;
#pragma unroll
    for (int n = 0; n < NSTATE; ++n) Arow[n] = -__expf(ap[n]);

    float h[NSTATE], P[NSTATE];
#pragma unroll
    for (int n = 0; n < NSTATE; ++n) { h[n] = 0.f; P[n] = 1.f; }

    const float* projb = proj + (size_t)b * LL * 224 + k * 56;
    const float* xcb = xc + (size_t)b * LL * DIN + d;
    const int t0 = s * CHLEN;

    for (int ws_ = 0; ws_ < CHLEN; ws_ += 8) {
        if (threadIdx.x < 448) {
            int wi = threadIdx.x / 56, c = threadIdx.x % 56;
            int pos = pos_of(k, t0 + ws_ + wi);
            lds[wi][c] = projb[(size_t)pos * 224 + c];
        }
        __syncthreads();
#pragma unroll
        for (int wi = 0; wi < 8; ++wi) {
            int pos = pos_of(k, t0 + ws_ + wi);
            float u = xcb[(size_t)pos * DIN];
            float dtr = bias;
#pragma unroll
            for (int r = 0; r < RRANK; ++r) dtr = fmaf(lds[wi][r], dtw[r], dtr);
            float delta = softplus_f(dtr);
            float du = delta * u;
#pragma unroll
            for (int n = 0; n < NSTATE; ++n) {
                float a = __expf(delta * Arow[n]);
                h[n] = fmaf(h[n], a, du * lds[wi][24 + n]);
                P[n] *= a;
            }
        }
        __syncthreads();
    }
    size_t base = ((size_t)((b * 4 + k) * NCHUNK + s)) * (DIN * NSTATE) + d * NSTATE;
#pragma unroll
    for (int n = 0; n < NSTATE; ++n) { Pout[base + n] = P[n]; Hloc[base + n] = h[n]; }
}

// NOTE: Hin may alias P (read-before-write per element, one thread per (bk,dn))
__global__ __launch_bounds__(256) void scan_phase2(
    const float* P, const float* __restrict__ Hl, float* Hin)
{
    const int idx = blockIdx.x * 256 + threadIdx.x;
    const int bk = idx / (DIN * NSTATE), dn = idx % (DIN * NSTATE);
    size_t base = (size_t)bk * NCHUNK * (DIN * NSTATE) + dn;
    float hin = 0.f;
#pragma unroll
    for (int s = 0; s < NCHUNK; ++s) {
        size_t o = base + (size_t)s * (DIN * NSTATE);
        float p = P[o];
        float hl = Hl[o];
        Hin[o] = hin;
        hin = fmaf(p, hin, hl);
    }
}

__global__ __launch_bounds__(768) void scan_phase3(
    const float* __restrict__ xc, const float* __restrict__ proj,
    const float* __restrict__ dtw_all, const float* __restrict__ dtb_all,
    const float* __restrict__ A_logs, const float* __restrict__ Ds,
    const float* __restrict__ Hin, float* __restrict__ ycomb)
{
    const int s = blockIdx.x, k = blockIdx.y, b = blockIdx.z;
    const int d = threadIdx.x;
    __shared__ float lds[8][56];

    float dtw[RRANK];
    const float* wp = dtw_all + ((size_t)(k * DIN + d)) * RRANK;
#pragma unroll
    for (int r = 0; r < RRANK; ++r) dtw[r] = wp[r];
    const float bias = dtb_all[k * DIN + d];
    const float Dval = Ds[k * DIN + d];
    float Arow[NSTATE];
    const float* ap = A_logs + ((size_t)(k * DIN + d)) * NSTATE;
#pragma unroll
    for (int n = 0; n < NSTATE; ++n) Arow[n] = -__expf(ap[n]);

    float h[NSTATE];
    size_t hbase = ((size_t)((b * 4 + k) * NCHUNK + s)) * (DIN * NSTATE) + d * NSTATE;
#pragma unroll
    for (int n = 0; n < NSTATE; ++n) h[n] = Hin[hbase + n];

    const float* projb = proj + (size_t)b * LL * 224 + k * 56;
    const float* xcb = xc + (size_t)b * LL * DIN + d;
    float* yb = ycomb + (size_t)b * LL * DIN + d;
    const int t0 = s * CHLEN;

    for (int ws_ = 0; ws_ < CHLEN; ws_ += 8) {
        if (threadIdx.x < 448) {
            int wi = threadIdx.x / 56, c = threadIdx.x % 56;
            int pos = pos_of(k, t0 + ws_ + wi);
            lds[wi][c] = projb[(size_t)pos * 224 + c];
        }
        __syncthreads();
#pragma unroll
        for (int wi = 0; wi < 8; ++wi) {
            int pos = pos_of(k, t0 + ws_ + wi);
            float u = xcb[(size_t)pos * DIN];
            float dtr = bias;
#pragma unroll
            for (int r = 0; r < RRANK; ++r) dtr = fmaf(lds[wi][r], dtw[r], dtr);
            float delta = softplus_f(dtr);
            float du = delta * u;
            float y = 0.f;
#pragma unroll
            for (int n = 0; n < NSTATE; ++n) {
                float a = __expf(delta * Arow[n]);
                h[n] = fmaf(h[n], a, du * lds[wi][24 + n]);
                y = fmaf(h[n], lds[wi][40 + n], y);
            }
            y = fmaf(Dval, u, y);
            atomicAdd(yb + (size_t)pos * DIN, y);
        }
        __syncthreads();
    }
}

// layernorm over Din + gate with silu(z).
__global__ __launch_bounds__(256) void ln_gate(
    const float* __restrict__ yc, const float* __restrict__ sz,
    const float* __restrict__ g, const float* __restrict__ bb,
    float* __restrict__ out)
{
    const int row = blockIdx.x;
    const float* yr = yc + (size_t)row * DIN;
    float v[3];
    float s = 0.f, q = 0.f;
#pragma unroll
    for (int i = 0; i < 3; ++i) {
        v[i] = yr[threadIdx.x + i * 256];
        s += v[i];
        q = fmaf(v[i], v[i], q);
    }
#pragma unroll
    for (int off = 32; off > 0; off >>= 1) {
        s += __shfl_down(s, off);
        q += __shfl_down(q, off);
    }
    __shared__ float red[10];
    const int lane = threadIdx.x & 63, wv = threadIdx.x >> 6;
    if (lane == 0) { red[wv] = s; red[4 + wv] = q; }
    __syncthreads();
    if (threadIdx.x == 0) {
        float S = red[0] + red[1] + red[2] + red[3];
        float Q = red[4] + red[5] + red[6] + red[7];
        float mu = S * (1.f / DIN);
        float var = Q * (1.f / DIN) - mu * mu;
        red[8] = mu;
        red[9] = rsqrtf(var + 1e-5f);
    }
    __syncthreads();
    const float mu = red[8], rs = red[9];
#pragma unroll
    for (int i = 0; i < 3; ++i) {
        int d = threadIdx.x + i * 256;
        float yn = fmaf((v[i] - mu) * rs, g[d], bb[d]);
        out[(size_t)row * DIN + d] = yn * sz[(size_t)row * DIN + d];
    }
}

extern "C" void kernel_launch(void* const* d_in, const int* in_sizes, int n_in,
                              void* d_out, int out_size, void* d_ws, size_t ws_size,
                              hipStream_t stream) {
    const float* x      = (const float*)d_in[0];
    const float* W_in   = (const float*)d_in[1];
    const float* conv_w = (const float*)d_in[2];
    const float* conv_b = (const float*)d_in[3];
    const float* xpw    = (const float*)d_in[4];
    const float* dtw    = (const float*)d_in[5];
    const float* dtb    = (const float*)d_in[6];
    const float* A_logs = (const float*)d_in[7];
    const float* Ds     = (const float*)d_in[8];
    const float* ln_g   = (const float*)d_in[9];
    const float* ln_b   = (const float*)d_in[10];
    const float* W_out  = (const float*)d_in[11];
    float* out = (float*)d_out;

    // per-image buffer sizes (floats)
    const size_t SZ_IMG  = (size_t)LL * DIN;                    // 3,145,728 (12 MB)
    const size_t SZ_PRJI = (size_t)LL * 224;                    //   917,504 (3.5 MB)
    const size_t SZ_SUMI = (size_t)4 * NCHUNK * DIN * NSTATE;   //   786,432 (3 MB)
    const size_t XPWT    = (size_t)DIN * 224;                   //   172,032
    const size_t perImg  = 3 * SZ_IMG + SZ_PRJI + 2 * SZ_SUMI;  // 11,010,048 floats

    // pick largest batch-chunk that fits in the provided workspace
    auto need = [&](int c) { return (perImg * (size_t)c + XPWT) * sizeof(float); };
    int BCH = (need(8) <= ws_size) ? 8
            : (need(4) <= ws_size) ? 4
            : (need(2) <= ws_size) ? 2 : 1;

    float* ws = (float*)d_ws;
    float* xm   = ws;                              // aliases y_comb
    float* szb  = xm  + (size_t)BCH * SZ_IMG;
    float* xc   = szb + (size_t)BCH * SZ_IMG;      // aliases y_norm
    float* proj = xc  + (size_t)BCH * SZ_IMG;
    float* Psum = proj + (size_t)BCH * SZ_PRJI;    // aliases Hin
    float* Hloc = Psum + (size_t)BCH * SZ_SUMI;
    float* xpwT = Hloc + (size_t)BCH * SZ_SUMI;

    transpose_xpw<<<(DIN * 224 + 255) / 256, 256, 0, stream>>>(xpw, xpwT);

    for (int b0 = 0; b0 < 8; b0 += BCH) {
        const int NB = BCH;
        const int M = NB * LL;
        // K1: xz = x @ W_in ; split xm / silu(z)
        gemm_f32<64, 1><<<dim3(1536 / 64, M / 128), 256, 0, stream>>>(
            x + (size_t)b0 * LL * 384, W_in, xm, szb, M, 384, 1536);
        // K2: depthwise conv + silu
        dwconv_silu<<<dim3(M, 3), 256, 0, stream>>>(xm, conv_w, conv_b, xc);
        // K3: proj = xc @ xpwT
        gemm_f32<32, 0><<<dim3(224 / 32, M / 128), 256, 0, stream>>>(
            xc, xpwT, proj, nullptr, M, DIN, 224);
        // zero y_comb (aliases xm; xm dead after conv)
        {
            int n4 = (int)(NB * SZ_IMG / 4);
            zero_fill<<<(n4 + 255) / 256, 256, 0, stream>>>((float4*)xm, n4);
        }
        // scan
        scan_phase1<<<dim3(NCHUNK, 4, NB), 768, 0, stream>>>(
            xc, proj, dtw, dtb, A_logs, Psum, Hloc);
        scan_phase2<<<(NB * 4 * DIN * NSTATE) / 256, 256, 0, stream>>>(
            Psum, Hloc, Psum);
        scan_phase3<<<dim3(NCHUNK, 4, NB), 768, 0, stream>>>(
            xc, proj, dtw, dtb, A_logs, Ds, Psum, xm);
        // LN + gate (writes y_norm into xc region)
        ln_gate<<<M, 256, 0, stream>>>(xm, szb, ln_g, ln_b, xc);
        // K5: out = y_norm @ W_out
        gemm_f32<64, 0><<<dim3(384 / 64, M / 128), 256, 0, stream>>>(
            xc, W_out, out + (size_t)b0 * LL * 384, nullptr, M, DIN, 384);
    }
}

// Round 3
// 1501.522 us; speedup vs baseline: 1.6171x; 1.6171x over previous
//
#include <hip/hip_runtime.h>
#include <cstddef>
#include <cstdint>

// ---------------------------------------------------------------------------
// VSSM (VMamba SS2D) forward. B=8, H=W=64, L=4096, D=384, Din=768, N=16,
// R=24, K=4 directions. Round 3: all three GEMMs moved to bf16 MFMA
// (mfma_f32_16x16x32_bf16, 128x128 tile, global_load_lds staging).
// Activations bf16 (xb, xm, z, xc, y_norm); proj + y_comb fp32.
// ---------------------------------------------------------------------------

#define LL 4096
#define DIN 768
#define NSTATE 16
#define RRANK 24
#define NCHUNK 16
#define CHLEN 256
#define PSTR 256   // padded proj row stride (224 real + 32 zero)

typedef __bf16 bf16_t;
typedef bf16_t bf16x8 __attribute__((ext_vector_type(8)));
typedef float f32x4 __attribute__((ext_vector_type(4)));

__device__ __forceinline__ float silu_f(float x) { return x / (1.f + __expf(-x)); }
__device__ __forceinline__ float softplus_f(float x) {
    return (x > 15.f) ? x : __logf(1.f + __expf(x));
}
__device__ __forceinline__ int pos_of(int k, int t) {
    int tt = (k >= 2) ? (LL - 1 - t) : t;
    if (k & 1) return (tt & 63) * 64 + (tt >> 6);  // transpose WH <-> HW
    return tt;
}
__device__ __forceinline__ void gl2lds16(const bf16_t* g, bf16_t* l) {
    __builtin_amdgcn_global_load_lds(
        (const __attribute__((address_space(1))) void*)g,
        (__attribute__((address_space(3))) void*)l, 16, 0, 0);
}

// ---------------------------------------------------------------------------
// bf16 MFMA GEMM: C[M,N] = A[M,K] @ Bt[N,K]^T. 128x128 tile, BK=32.
// 256 threads = 4 waves (2x2), each wave 64x64 via 4x4 frags of 16x16x32.
// EPI==0: fp32 store to o0 with ldc = N = gridDim.x*128
// EPI==1: split (K1): col<768 -> o0 bf16 (xm); col>=768 -> o1 bf16 = silu (z)
// ---------------------------------------------------------------------------
template<int EPI>
__global__ __launch_bounds__(256) void gemm_bf16(
    const bf16_t* __restrict__ A, const bf16_t* __restrict__ Bt,
    void* __restrict__ o0, void* __restrict__ o1, int K)
{
    __shared__ __align__(16) bf16_t As[128 * 32];
    __shared__ __align__(16) bf16_t Bs[128 * 32];
    const int tid = threadIdx.x;
    const int bx = blockIdx.x, by = blockIdx.y;
    const int w = tid >> 6, lane = tid & 63;
    const int wy = w >> 1, wx = w & 1;
    const int lm = lane & 15, lg = lane >> 4;
    const int N = gridDim.x * 128;

    f32x4 acc[4][4];
#pragma unroll
    for (int i = 0; i < 4; ++i)
#pragma unroll
        for (int j = 0; j < 4; ++j) acc[i][j] = (f32x4){0.f, 0.f, 0.f, 0.f};

    const bf16_t* Ab = A + (size_t)by * 128 * K;
    const bf16_t* Bb = Bt + (size_t)bx * 128 * K;
    // staging: flat f in [0,512): row = f>>2, kgroup = f&3; lds elems = f*8
    const int r1 = tid >> 2, r2 = (tid + 256) >> 2, g1 = tid & 3;
    bf16_t* lA1 = As + (size_t)(tid & ~63) * 8;
    bf16_t* lA2 = As + (size_t)((tid + 256) & ~63) * 8;
    bf16_t* lB1 = Bs + (size_t)(tid & ~63) * 8;
    bf16_t* lB2 = Bs + (size_t)((tid + 256) & ~63) * 8;

    for (int kt = 0; kt < K; kt += 32) {
        __syncthreads();
        gl2lds16(Ab + (size_t)r1 * K + kt + g1 * 8, lA1);
        gl2lds16(Ab + (size_t)r2 * K + kt + g1 * 8, lA2);
        gl2lds16(Bb + (size_t)r1 * K + kt + g1 * 8, lB1);
        gl2lds16(Bb + (size_t)r2 * K + kt + g1 * 8, lB2);
        __syncthreads();
        bf16x8 af[4], bfr[4];
#pragma unroll
        for (int i = 0; i < 4; ++i) {
            af[i]  = *(const bf16x8*)(As + (size_t)(wy * 64 + i * 16 + lm) * 32 + lg * 8);
            bfr[i] = *(const bf16x8*)(Bs + (size_t)(wx * 64 + i * 16 + lm) * 32 + lg * 8);
        }
#pragma unroll
        for (int i = 0; i < 4; ++i)
#pragma unroll
            for (int j = 0; j < 4; ++j)
                acc[i][j] = __builtin_amdgcn_mfma_f32_16x16x32_bf16(
                    af[i], bfr[j], acc[i][j], 0, 0, 0);
    }

#pragma unroll
    for (int i = 0; i < 4; ++i) {
        int row0 = by * 128 + wy * 64 + i * 16 + lg * 4;
#pragma unroll
        for (int j = 0; j < 4; ++j) {
            int col = bx * 128 + wx * 64 + j * 16 + lm;
#pragma unroll
            for (int r = 0; r < 4; ++r) {
                float v = acc[i][j][r];
                int m = row0 + r;
                if (EPI == 0) {
                    ((float*)o0)[(size_t)m * N + col] = v;
                } else {
                    if (col < DIN) ((bf16_t*)o0)[(size_t)m * DIN + col] = (bf16_t)v;
                    else ((bf16_t*)o1)[(size_t)m * DIN + (col - DIN)] = (bf16_t)silu_f(v);
                }
            }
        }
    }
}

// fp32 -> bf16 elementwise (n divisible by 4)
__global__ __launch_bounds__(256) void cvt_x(
    const float* __restrict__ src, bf16_t* __restrict__ dst, int n4)
{
    int i = blockIdx.x * 256 + threadIdx.x;
    if (i >= n4) return;
    float4 v = ((const float4*)src)[i];
    dst[i * 4 + 0] = (bf16_t)v.x; dst[i * 4 + 1] = (bf16_t)v.y;
    dst[i * 4 + 2] = (bf16_t)v.z; dst[i * 4 + 3] = (bf16_t)v.w;
}

// dst[n][k] = (bf16)src[k][n]   (src is [K][N] row-major)
__global__ __launch_bounds__(256) void cvt_transpose(
    const float* __restrict__ src, bf16_t* __restrict__ dst, int K, int N)
{
    int idx = blockIdx.x * 256 + threadIdx.x;
    if (idx >= K * N) return;
    int n = idx / K, k = idx % K;
    dst[idx] = (bf16_t)src[(size_t)k * N + n];
}

// x_proj_weight (4,56,768) flat -> bf16 [256][768], rows 224..255 zeroed
__global__ __launch_bounds__(256) void cvt_xpw(
    const float* __restrict__ src, bf16_t* __restrict__ dst)
{
    int idx = blockIdx.x * 256 + threadIdx.x;
    if (idx >= 256 * 768) return;
    dst[idx] = (idx < 224 * 768) ? (bf16_t)src[idx] : (bf16_t)0.f;
}

// depthwise 3x3 conv (pad 1) + silu, bf16 in/out
__global__ __launch_bounds__(256) void dwconv_silu(
    const bf16_t* __restrict__ xm, const float* __restrict__ cw,
    const float* __restrict__ cb, bf16_t* __restrict__ xc)
{
    const int bl = blockIdx.x;
    const int d = blockIdx.y * 256 + threadIdx.x;
    const int b = bl >> 12, l = bl & 4095;
    const int h = l >> 6, wq = l & 63;
    float acc = cb[d];
#pragma unroll
    for (int i = 0; i < 3; ++i) {
        int hh = h + i - 1;
        if (hh < 0 || hh > 63) continue;
#pragma unroll
        for (int j = 0; j < 3; ++j) {
            int ww = wq + j - 1;
            if (ww < 0 || ww > 63) continue;
            acc = fmaf((float)xm[((size_t)(b << 12) + (hh << 6) + ww) * DIN + d],
                       cw[d * 9 + i * 3 + j], acc);
        }
    }
    xc[(size_t)bl * DIN + d] = (bf16_t)silu_f(acc);
}

__global__ void zero_fill(float4* __restrict__ p, int n4) {
    int i = blockIdx.x * 256 + threadIdx.x;
    if (i < n4) p[i] = make_float4(0.f, 0.f, 0.f, 0.f);
}

// ---------------------------------------------------------------------------
// Chunked selective scan (3 phases). xc bf16, proj fp32 stride PSTR.
// ---------------------------------------------------------------------------
__global__ __launch_bounds__(768) void scan_phase1(
    const bf16_t* __restrict__ xc, const float* __restrict__ proj,
    const float* __restrict__ dtw_all, const float* __restrict__ dtb_all,
    const float* __restrict__ A_logs,
    float* __restrict__ Pout, float* __restrict__ Hloc)
{
    const int s = blockIdx.x, k = blockIdx.y, b = blockIdx.z;
    const int d = threadIdx.x;
    __shared__ float lds[8][56];

    float dtw[RRANK];
    const float* wp = dtw_all + ((size_t)(k * DIN + d)) * RRANK;
#pragma unroll
    for (int r = 0; r < RRANK; ++r) dtw[r] = wp[r];
    const float bias = dtb_all[k * DIN + d];
    float Arow[NSTATE];
    const float* ap = A_logs + ((size_t)(k * DIN + d)) * NSTATE;
#pragma unroll
    for (int n = 0; n < NSTATE; ++n) Arow[n] = -__expf(ap[n]);

    float h[NSTATE], P[NSTATE];
#pragma unroll
    for (int n = 0; n < NSTATE; ++n) { h[n] = 0.f; P[n] = 1.f; }

    const float* projb = proj + (size_t)b * LL * PSTR + k * 56;
    const bf16_t* xcb = xc + (size_t)b * LL * DIN + d;
    const int t0 = s * CHLEN;

    for (int ws_ = 0; ws_ < CHLEN; ws_ += 8) {
        if (threadIdx.x < 448) {
            int wi = threadIdx.x / 56, c = threadIdx.x % 56;
            int pos = pos_of(k, t0 + ws_ + wi);
            lds[wi][c] = projb[(size_t)pos * PSTR + c];
        }
        __syncthreads();
#pragma unroll
        for (int wi = 0; wi < 8; ++wi) {
            int pos = pos_of(k, t0 + ws_ + wi);
            float u = (float)xcb[(size_t)pos * DIN];
            float dtr = bias;
#pragma unroll
            for (int r = 0; r < RRANK; ++r) dtr = fmaf(lds[wi][r], dtw[r], dtr);
            float delta = softplus_f(dtr);
            float du = delta * u;
#pragma unroll
            for (int n = 0; n < NSTATE; ++n) {
                float a = __expf(delta * Arow[n]);
                h[n] = fmaf(h[n], a, du * lds[wi][24 + n]);
                P[n] *= a;
            }
        }
        __syncthreads();
    }
    size_t base = ((size_t)((b * 4 + k) * NCHUNK + s)) * (DIN * NSTATE) + d * NSTATE;
#pragma unroll
    for (int n = 0; n < NSTATE; ++n) { Pout[base + n] = P[n]; Hloc[base + n] = h[n]; }
}

// NOTE: Hin may alias P (read-before-write per element)
__global__ __launch_bounds__(256) void scan_phase2(
    const float* P, const float* __restrict__ Hl, float* Hin)
{
    const int idx = blockIdx.x * 256 + threadIdx.x;
    const int bk = idx / (DIN * NSTATE), dn = idx % (DIN * NSTATE);
    size_t base = (size_t)bk * NCHUNK * (DIN * NSTATE) + dn;
    float hin = 0.f;
#pragma unroll
    for (int s = 0; s < NCHUNK; ++s) {
        size_t o = base + (size_t)s * (DIN * NSTATE);
        float p = P[o];
        float hl = Hl[o];
        Hin[o] = hin;
        hin = fmaf(p, hin, hl);
    }
}

__global__ __launch_bounds__(768) void scan_phase3(
    const bf16_t* __restrict__ xc, const float* __restrict__ proj,
    const float* __restrict__ dtw_all, const float* __restrict__ dtb_all,
    const float* __restrict__ A_logs, const float* __restrict__ Ds,
    const float* __restrict__ Hin, float* __restrict__ ycomb)
{
    const int s = blockIdx.x, k = blockIdx.y, b = blockIdx.z;
    const int d = threadIdx.x;
    __shared__ float lds[8][56];

    float dtw[RRANK];
    const float* wp = dtw_all + ((size_t)(k * DIN + d)) * RRANK;
#pragma unroll
    for (int r = 0; r < RRANK; ++r) dtw[r] = wp[r];
    const float bias = dtb_all[k * DIN + d];
    const float Dval = Ds[k * DIN + d];
    float Arow[NSTATE];
    const float* ap = A_logs + ((size_t)(k * DIN + d)) * NSTATE;
#pragma unroll
    for (int n = 0; n < NSTATE; ++n) Arow[n] = -__expf(ap[n]);

    float h[NSTATE];
    size_t hbase = ((size_t)((b * 4 + k) * NCHUNK + s)) * (DIN * NSTATE) + d * NSTATE;
#pragma unroll
    for (int n = 0; n < NSTATE; ++n) h[n] = Hin[hbase + n];

    const float* projb = proj + (size_t)b * LL * PSTR + k * 56;
    const bf16_t* xcb = xc + (size_t)b * LL * DIN + d;
    float* yb = ycomb + (size_t)b * LL * DIN + d;
    const int t0 = s * CHLEN;

    for (int ws_ = 0; ws_ < CHLEN; ws_ += 8) {
        if (threadIdx.x < 448) {
            int wi = threadIdx.x / 56, c = threadIdx.x % 56;
            int pos = pos_of(k, t0 + ws_ + wi);
            lds[wi][c] = projb[(size_t)pos * PSTR + c];
        }
        __syncthreads();
#pragma unroll
        for (int wi = 0; wi < 8; ++wi) {
            int pos = pos_of(k, t0 + ws_ + wi);
            float u = (float)xcb[(size_t)pos * DIN];
            float dtr = bias;
#pragma unroll
            for (int r = 0; r < RRANK; ++r) dtr = fmaf(lds[wi][r], dtw[r], dtr);
            float delta = softplus_f(dtr);
            float du = delta * u;
            float y = 0.f;
#pragma unroll
            for (int n = 0; n < NSTATE; ++n) {
                float a = __expf(delta * Arow[n]);
                h[n] = fmaf(h[n], a, du * lds[wi][24 + n]);
                y = fmaf(h[n], lds[wi][40 + n], y);
            }
            y = fmaf(Dval, u, y);
            atomicAdd(yb + (size_t)pos * DIN, y);
        }
        __syncthreads();
    }
}

// layernorm over Din + gate with silu(z) (z already silu'd, bf16); out bf16
__global__ __launch_bounds__(256) void ln_gate(
    const float* __restrict__ yc, const bf16_t* __restrict__ zb,
    const float* __restrict__ g, const float* __restrict__ bb,
    bf16_t* __restrict__ out)
{
    const int row = blockIdx.x;
    const float* yr = yc + (size_t)row * DIN;
    float v[3];
    float s = 0.f, q = 0.f;
#pragma unroll
    for (int i = 0; i < 3; ++i) {
        v[i] = yr[threadIdx.x + i * 256];
        s += v[i];
        q = fmaf(v[i], v[i], q);
    }
#pragma unroll
    for (int off = 32; off > 0; off >>= 1) {
        s += __shfl_down(s, off);
        q += __shfl_down(q, off);
    }
    __shared__ float red[10];
    const int lane = threadIdx.x & 63, wv = threadIdx.x >> 6;
    if (lane == 0) { red[wv] = s; red[4 + wv] = q; }
    __syncthreads();
    if (threadIdx.x == 0) {
        float S = red[0] + red[1] + red[2] + red[3];
        float Q = red[4] + red[5] + red[6] + red[7];
        float mu = S * (1.f / DIN);
        float var = Q * (1.f / DIN) - mu * mu;
        red[8] = mu;
        red[9] = rsqrtf(var + 1e-5f);
    }
    __syncthreads();
    const float mu = red[8], rs = red[9];
#pragma unroll
    for (int i = 0; i < 3; ++i) {
        int d = threadIdx.x + i * 256;
        float yn = fmaf((v[i] - mu) * rs, g[d], bb[d]);
        out[(size_t)row * DIN + d] = (bf16_t)(yn * (float)zb[(size_t)row * DIN + d]);
    }
}

extern "C" void kernel_launch(void* const* d_in, const int* in_sizes, int n_in,
                              void* d_out, int out_size, void* d_ws, size_t ws_size,
                              hipStream_t stream) {
    const float* x      = (const float*)d_in[0];
    const float* W_in   = (const float*)d_in[1];
    const float* conv_w = (const float*)d_in[2];
    const float* conv_b = (const float*)d_in[3];
    const float* xpw    = (const float*)d_in[4];
    const float* dtw    = (const float*)d_in[5];
    const float* dtb    = (const float*)d_in[6];
    const float* A_logs = (const float*)d_in[7];
    const float* Ds     = (const float*)d_in[8];
    const float* ln_g   = (const float*)d_in[9];
    const float* ln_b   = (const float*)d_in[10];
    const float* W_out  = (const float*)d_in[11];
    float* out = (float*)d_out;

    // per-image byte sizes
    const size_t B_XB   = (size_t)LL * 384 * 2;          //  3,145,728
    const size_t B_XM   = (size_t)LL * DIN * 2;          //  6,291,456
    const size_t B_YC   = (size_t)LL * DIN * 4;          // 12,582,912 (R region)
    const size_t B_Z    = B_XM;
    const size_t B_XC   = B_XM;
    const size_t B_PRJ  = (size_t)LL * PSTR * 4;         //  4,194,304
    const size_t B_SUM  = (size_t)4 * NCHUNK * DIN * NSTATE * 4;  // 3,145,728
    const size_t B_WTS  = (size_t)1536 * 384 * 2 + (size_t)256 * 768 * 2
                        + (size_t)384 * 768 * 2;         //  2,162,688
    const size_t perImg = B_YC + B_Z + B_XC + B_PRJ + 2 * B_SUM;  // 35,651,584

    auto need = [&](int c) { return perImg * (size_t)c + B_WTS; };
    int BCH = (need(8) <= ws_size) ? 8
            : (need(4) <= ws_size) ? 4
            : (need(2) <= ws_size) ? 2 : 1;

    char* ws = (char*)d_ws;
    char*   R     = ws;                         // holds xb+xm, then y_comb
    bf16_t* xb    = (bf16_t*)R;
    bf16_t* xm    = (bf16_t*)(R + (size_t)BCH * B_XB);
    float*  ycomb = (float*)R;
    bf16_t* zbuf  = (bf16_t*)(R + (size_t)BCH * B_YC);
    bf16_t* xc    = (bf16_t*)((char*)zbuf + (size_t)BCH * B_Z);   // also y_norm
    float*  proj  = (float*)((char*)xc + (size_t)BCH * B_XC);
    float*  Psum  = (float*)((char*)proj + (size_t)BCH * B_PRJ);  // aliases Hin
    float*  Hloc  = (float*)((char*)Psum + (size_t)BCH * B_SUM);
    bf16_t* WinT  = (bf16_t*)((char*)Hloc + (size_t)BCH * B_SUM);
    bf16_t* xpwb  = WinT + (size_t)1536 * 384;
    bf16_t* WoutT = xpwb + (size_t)256 * 768;

    // weight prep (once per call)
    cvt_transpose<<<(1536 * 384) / 256, 256, 0, stream>>>(W_in, WinT, 384, 1536);
    cvt_xpw<<<(256 * 768) / 256, 256, 0, stream>>>(xpw, xpwb);
    cvt_transpose<<<(768 * 384) / 256, 256, 0, stream>>>(W_out, WoutT, 768, 384);

    for (int b0 = 0; b0 < 8; b0 += BCH) {
        const int NB = BCH;
        const int M = NB * LL;
        // convert x chunk to bf16
        cvt_x<<<(M * 384 / 4 + 255) / 256, 256, 0, stream>>>(
            x + (size_t)b0 * LL * 384, xb, M * 384 / 4);
        // K1: xz = xb @ W_in ; split xm / silu(z), both bf16
        gemm_bf16<1><<<dim3(12, M / 128), 256, 0, stream>>>(
            xb, WinT, xm, zbuf, 384);
        // K2: depthwise conv + silu
        dwconv_silu<<<dim3(M, 3), 256, 0, stream>>>(xm, conv_w, conv_b, xc);
        // K3: proj = xc @ xpw^T (fp32 out, stride 256)
        gemm_bf16<0><<<dim3(2, M / 128), 256, 0, stream>>>(
            xc, xpwb, proj, nullptr, 768);
        // zero y_comb (aliases xb+xm region, both dead now)
        {
            int n4 = (int)((size_t)NB * B_YC / 16);
            zero_fill<<<(n4 + 255) / 256, 256, 0, stream>>>((float4*)ycomb, n4);
        }
        // scan
        scan_phase1<<<dim3(NCHUNK, 4, NB), 768, 0, stream>>>(
            xc, proj, dtw, dtb, A_logs, Psum, Hloc);
        scan_phase2<<<(NB * 4 * DIN * NSTATE) / 256, 256, 0, stream>>>(
            Psum, Hloc, Psum);
        scan_phase3<<<dim3(NCHUNK, 4, NB), 768, 0, stream>>>(
            xc, proj, dtw, dtb, A_logs, Ds, Psum, ycomb);
        // LN + gate -> y_norm bf16 (into xc region, xc dead after phase3)
        ln_gate<<<M, 256, 0, stream>>>(ycomb, zbuf, ln_g, ln_b, xc);
        // K5: out = y_norm @ W_out (fp32 out, ldc = 384)
        gemm_bf16<0><<<dim3(3, M / 128), 256, 0, stream>>>(
            xc, WoutT, out + (size_t)b0 * LL * 384, nullptr, 768);
    }
}